// Round 3
// baseline (218.570 us; speedup 1.0000x reference)
//
#include <hip/hip_runtime.h>
#include <hip/hip_bf16.h>
#include <math.h>

#define S_LEN 1024
#define BATCH 2
#define HIDDEN 2048
#define NQH 32
#define NKVH 8
#define HD 64
#define LDQKV 3072          // Q(2048) | K(512) | V(512)
#define M_ROWS (BATCH * S_LEN)

typedef __attribute__((ext_vector_type(8))) short bf16x8;
typedef __attribute__((ext_vector_type(4))) float f32x4;

typedef unsigned int uint32_g __attribute__((address_space(1)));
typedef unsigned int uint32_l __attribute__((address_space(3)));

// async global->LDS, 16 B per lane; lds base MUST be wave-uniform,
// HW writes lane i at base + i*16 (m97/m104 semantics).
static __device__ __forceinline__ void load_lds16(const void* g, void* l) {
    __builtin_amdgcn_global_load_lds((const uint32_g*)g, (uint32_l*)l, 16, 0, 0);
}

static __device__ __forceinline__ short f2bf(float f) {
    union { __hip_bfloat16 h; short s; } cv;
    cv.h = __float2bfloat16(f);   // RNE
    return cv.s;
}

// ---------------------------------------------------------------------------
// Single pre-pass launch:
//  z=0..3 : weights fp32 [K][N] -> bf16 transposed [N][K] (64x64 LDS tiles)
//  z=4    : X fp32->bf16 flat convert + RoPE cos/sin table
// ---------------------------------------------------------------------------
__global__ __launch_bounds__(256) void conv_all_kernel(
    const float* __restrict__ X,
    const float* __restrict__ Wq, const float* __restrict__ Wk,
    const float* __restrict__ Wv, const float* __restrict__ Wo,
    short* __restrict__ Xb, short* __restrict__ Wqkvt, short* __restrict__ Wot,
    float2* __restrict__ cs2)
{
    __shared__ short Ts[64][68];
    const int tid = threadIdx.x;

    if (blockIdx.z == 4) {
        int flat = blockIdx.y * 32 + blockIdx.x;        // 0..1023
        size_t base = (size_t)flat * 4096 + (size_t)tid * 16;
        #pragma unroll
        for (int rep = 0; rep < 2; ++rep) {
            size_t i = base + rep * 8;
            float4 a = *reinterpret_cast<const float4*>(X + i);
            float4 b = *reinterpret_cast<const float4*>(X + i + 4);
            union { bf16x8 v; short s[8]; } t;
            t.s[0] = f2bf(a.x); t.s[1] = f2bf(a.y); t.s[2] = f2bf(a.z); t.s[3] = f2bf(a.w);
            t.s[4] = f2bf(b.x); t.s[5] = f2bf(b.y); t.s[6] = f2bf(b.z); t.s[7] = f2bf(b.w);
            *reinterpret_cast<bf16x8*>(Xb + i) = t.v;
        }
        if (flat < 128) {
            int g = flat * 256 + tid;                   // 32768 entries
            int s = g >> 5, i = g & 31;
            float inv_freq = 1.0f / powf(10000.0f, (float)i / 32.0f);
            float freq = (float)s * inv_freq;           // fp32 like reference
            double sn, cs;
            sincos((double)freq, &sn, &cs);
            cs2[g] = make_float2((float)cs, (float)sn);
        }
        return;
    }

    const float* src; short* dst; int N;
    switch (blockIdx.z) {
        case 0: src = Wq; dst = Wqkvt;                         N = 2048; break;
        case 1: src = Wk; dst = Wqkvt + (size_t)2048 * 2048;   N = 512;  break;
        case 2: src = Wv; dst = Wqkvt + (size_t)2560 * 2048;   N = 512;  break;
        default: src = Wo; dst = Wot;                          N = 2048; break;
    }
    const int n0 = blockIdx.x * 64, k0 = blockIdx.y * 64;
    if (n0 >= N) return;

    #pragma unroll
    for (int rep = 0; rep < 4; ++rep) {
        int idx = rep * 256 + tid;
        int row = idx >> 4, c4 = (idx & 15) * 4;
        float4 v = *reinterpret_cast<const float4*>(
            src + (size_t)(k0 + row) * N + n0 + c4);
        ushort4 u;
        u.x = (unsigned short)f2bf(v.x); u.y = (unsigned short)f2bf(v.y);
        u.z = (unsigned short)f2bf(v.z); u.w = (unsigned short)f2bf(v.w);
        *reinterpret_cast<ushort4*>(&Ts[row][c4]) = u;
    }
    __syncthreads();
    #pragma unroll
    for (int rep = 0; rep < 2; ++rep) {
        int idx = rep * 256 + tid;
        int n = idx >> 3, kc = (idx & 7) * 8;
        union { bf16x8 v; short s[8]; } t;
        #pragma unroll
        for (int j = 0; j < 8; ++j) t.s[j] = Ts[kc + j][n];
        *reinterpret_cast<bf16x8*>(dst + (size_t)(n0 + n) * 2048 + k0 + kc) = t.v;
    }
}

// ---------------------------------------------------------------------------
// bf16 MFMA GEMM v2: 128x128 tile (m97-density structure), BK=64, async
// global_load_lds w16 into unpadded XOR-swizzled LDS (chunk ^= row&7).
// 4 waves in 2x2 (wr,wc); each wave owns a 64x64 sub-tile, acc[4][4]:
// 32 MFMA per 2-barrier K-step per wave (2x the old 128x64 density).
// ROPE_BF16 epilogues: RoPE for Q/K heads (head = (n0+wc*64)/64, tiles stay
// head-aligned); V tiles (n0>=2560) transpose 2 kv-heads via 128x136 LDS.
// ---------------------------------------------------------------------------
template <bool ROPE_BF16>
__global__ __launch_bounds__(256) void gemm_bf16_kernel(
    const short* __restrict__ A, const short* __restrict__ Bt,
    float* __restrict__ C, short* __restrict__ Cb,
    short* __restrict__ vt_g,
    const float2* __restrict__ cs2, int K, int ldc)
{
    const int n0 = blockIdx.x * 128, m0 = blockIdx.y * 128;
    const int tid = threadIdx.x;
    const int w = tid >> 6, lane = tid & 63;
    const int wr = w >> 1, wc = w & 1;
    const int m15 = lane & 15, q4 = lane >> 4;

    __shared__ short SL[128 * 136];            // As|Bs (32 KB) / VT (34.8 KB)
    short (*As)[64] = (short(*)[64])SL;
    short (*Bs)[64] = (short(*)[64])(SL + 128 * 64);

    f32x4 acc[4][4];
    #pragma unroll
    for (int i = 0; i < 4; ++i)
        #pragma unroll
        for (int j = 0; j < 4; ++j) acc[i][j] = (f32x4){0.f, 0.f, 0.f, 0.f};

    const int srow = lane >> 3;      // row within 8-row issue
    const int pchunk = lane & 7;     // physical 16B chunk

    for (int k0 = 0; k0 < K; k0 += 64) {
        __syncthreads();             // prev compute done; LDS reusable
        #pragma unroll
        for (int r = 0; r < 4; ++r) {
            int row = (w * 4 + r) * 8 + srow;          // 0..127
            int lchunk = pchunk ^ (row & 7);
            load_lds16(A + (size_t)(m0 + row) * K + k0 + lchunk * 8,
                       &As[(w * 4 + r) * 8][0]);
            load_lds16(Bt + (size_t)(n0 + row) * K + k0 + lchunk * 8,
                       &Bs[(w * 4 + r) * 8][0]);
        }
        __syncthreads();             // drains vmcnt -> staging visible

        #pragma unroll
        for (int ch = 0; ch < 2; ++ch) {
            bf16x8 af[4], bf[4];
            #pragma unroll
            for (int mt = 0; mt < 4; ++mt) {
                int row = wr * 64 + mt * 16 + m15;
                af[mt] = *reinterpret_cast<const bf16x8*>(
                    &As[row][(((ch * 4 + q4) ^ (row & 7))) * 8]);
            }
            #pragma unroll
            for (int nt = 0; nt < 4; ++nt) {
                int row = wc * 64 + nt * 16 + m15;
                bf[nt] = *reinterpret_cast<const bf16x8*>(
                    &Bs[row][(((ch * 4 + q4) ^ (row & 7))) * 8]);
            }
            #pragma unroll
            for (int mt = 0; mt < 4; ++mt)
                #pragma unroll
                for (int nt = 0; nt < 4; ++nt)
                    acc[mt][nt] = __builtin_amdgcn_mfma_f32_16x16x32_bf16(
                        af[mt], bf[nt], acc[mt][nt], 0, 0, 0);
        }
    }

    if (!ROPE_BF16) {
        #pragma unroll
        for (int mt = 0; mt < 4; ++mt)
            #pragma unroll
            for (int nt = 0; nt < 4; ++nt)
                #pragma unroll
                for (int reg = 0; reg < 4; ++reg)
                    C[(size_t)(m0 + wr * 64 + mt * 16 + q4 * 4 + reg) * ldc
                      + n0 + wc * 64 + nt * 16 + m15] = acc[mt][nt][reg];
    } else if (n0 < 2560) {
        // Q or K head: rotate (x1 = nt 0,1; x2 = nt 2,3). Wave's 64 cols are
        // exactly one head (n0 multiple of 128, heads 64-wide).
        #pragma unroll
        for (int mt = 0; mt < 4; ++mt) {
            #pragma unroll
            for (int reg = 0; reg < 4; ++reg) {
                int row = m0 + wr * 64 + mt * 16 + q4 * 4 + reg;
                int s = row & (S_LEN - 1);
                float2 t0 = cs2[s * 32 + m15];
                float2 t1 = cs2[s * 32 + 16 + m15];
                float a0 = acc[mt][0][reg], a1 = acc[mt][1][reg];
                float a2 = acc[mt][2][reg], a3 = acc[mt][3][reg];
                size_t base = (size_t)row * ldc + n0 + wc * 64 + m15;
                Cb[base +  0] = f2bf(a0 * t0.x - a2 * t0.y);
                Cb[base + 16] = f2bf(a1 * t1.x - a3 * t1.y);
                Cb[base + 32] = f2bf(a2 * t0.x + a0 * t0.y);
                Cb[base + 48] = f2bf(a3 * t1.x + a1 * t1.y);
            }
        }
    } else {
        // V tile (2 kv-heads): transpose via LDS,
        // write vt_g[(b*8+kvh)*64+dim][1024]
        __syncthreads();             // all waves done reading As/Bs
        short (*VT)[136] = (short(*)[136])SL;   // [128 col][128 row +8 pad]
        #pragma unroll
        for (int mt = 0; mt < 4; ++mt) {
            #pragma unroll
            for (int nt = 0; nt < 4; ++nt) {
                ushort4 u;
                u.x = (unsigned short)f2bf(acc[mt][nt][0]);
                u.y = (unsigned short)f2bf(acc[mt][nt][1]);
                u.z = (unsigned short)f2bf(acc[mt][nt][2]);
                u.w = (unsigned short)f2bf(acc[mt][nt][3]);
                *reinterpret_cast<ushort4*>(
                    &VT[wc * 64 + nt * 16 + m15]
                       [wr * 64 + mt * 16 + q4 * 4]) = u;
            }
        }
        __syncthreads();
        const int kvh0 = (n0 - 2560) >> 6;
        const int b = m0 >> 10, k0loc = m0 & (S_LEN - 1);
        const int dim = tid >> 2, kc = (tid & 3) * 32;
        #pragma unroll
        for (int hh = 0; hh < 2; ++hh) {
            short* dst = vt_g
                + (size_t)((b * 8 + kvh0 + hh) * 64 + dim) * S_LEN + k0loc + kc;
            #pragma unroll
            for (int u = 0; u < 4; ++u)
                *reinterpret_cast<bf16x8*>(dst + u * 8) =
                    *reinterpret_cast<const bf16x8*>(&VT[hh * 64 + dim][kc + u * 8]);
        }
    }
}

// ---------------------------------------------------------------------------
// Causal GQA attention v5: paired q-tiles, 8 waves (512 thr) per block.
// Block (i, h, b): waves 0-3 own heavy q-tile qtB=15-i (16 q-rows each),
// waves 4-7 own light q-tile qtA=i (idle for t > qtA, still stage+barrier).
// Grid 8x32x2 = 512 blocks x 8 waves = 16 waves/CU = 4 waves/SIMD.
// K/V ping-pong staged via global_load_lds w16, prefetch-before-compute,
// one barrier per tile. fp32 no-max softmax p = exp2(acc * 0.125*log2e),
// clamp 80, analytic causal mask. (unchanged — known-good)
// ---------------------------------------------------------------------------
__global__ __launch_bounds__(512) void attn_kernel(
    const short* __restrict__ qkvb, const short* __restrict__ vt_g,
    short* __restrict__ attn_b)
{
    const int i  = blockIdx.x;        // 0..7
    const int h  = blockIdx.y;
    const int b  = blockIdx.z;
    const int qtA = i;                // 0..7   (light q-tile)
    const int qtB = 15 - i;           // 15..8  (heavy q-tile)
    const int tid = threadIdx.x;
    const int w = tid >> 6, lane = tid & 63;
    const int kvh = h >> 2;
    const int m15 = lane & 15, q4 = lane >> 4;

    __shared__ short Ks[2][64][64];   // [buf][key][dim], XOR-swizzled chunks
    __shared__ short Vt[2][64][64];   // [buf][dim][key], XOR-swizzled chunks
    __shared__ float Ps[8][16][68];   // per-wave P [row][key] fp32

    // wave -> q-tile assignment
    const int qt_w = (w < 4) ? qtB : qtA;
    const int rowbase = qt_w * 64 + (w & 3) * 16;

    const bf16x8 qf0 = *reinterpret_cast<const bf16x8*>(
        qkvb + (size_t)(b * S_LEN + rowbase + m15) * LDQKV + h * HD + q4 * 8);
    const bf16x8 qf1 = *reinterpret_cast<const bf16x8*>(
        qkvb + (size_t)(b * S_LEN + rowbase + m15) * LDQKV + h * HD + 32 + q4 * 8);

    f32x4 o4[4];
    #pragma unroll
    for (int k = 0; k < 4; ++k) o4[k] = (f32x4){0.f, 0.f, 0.f, 0.f};
    float lsum[4] = {0.f, 0.f, 0.f, 0.f};

    const int r8 = lane >> 3, p8 = lane & 7;
    const int lch = (p8 ^ r8) * 8;    // logical chunk offset to fetch (shorts)
    const short* kbase = qkvb + (size_t)(b * S_LEN) * LDQKV + 2048 + kvh * HD;
    const short* vbase = vt_g + (size_t)(b * 8 + kvh) * 64 * S_LEN;

// wave w stages Ks rows w*8..+7 (keys) and Vt rows w*8..+7 (dims) of buf
#define STAGE(bf_, t) do {                                                    \
    int row_ = w * 8 + r8;                                                    \
    load_lds16(kbase + (size_t)((t) * 64 + row_) * LDQKV + lch,               \
               &Ks[bf_][w * 8][0]);                                           \
    load_lds16(vbase + (size_t)row_ * S_LEN + (t) * 64 + lch,                 \
               &Vt[bf_][w * 8][0]);                                           \
} while (0)

// QK^T + mask + exp into per-wave Ps; P->bf16; PV. Identical math to v3/v4.
#define COMPUTE(bf_, t) do {                                                  \
    const int xr_ = m15 & 7;                                                  \
    bf16x8 pf_[2];                                                            \
    _Pragma("unroll")                                                         \
    for (int nt = 0; nt < 4; ++nt) {                                          \
        f32x4 acc = (f32x4){0.f, 0.f, 0.f, 0.f};                              \
        bf16x8 kf0 = *reinterpret_cast<const bf16x8*>(                        \
            &Ks[bf_][nt * 16 + m15][(q4 ^ xr_) * 8]);                         \
        bf16x8 kf1 = *reinterpret_cast<const bf16x8*>(                        \
            &Ks[bf_][nt * 16 + m15][((4 + q4) ^ xr_) * 8]);                   \
        acc = __builtin_amdgcn_mfma_f32_16x16x32_bf16(qf0, kf0, acc, 0, 0, 0);\
        acc = __builtin_amdgcn_mfma_f32_16x16x32_bf16(qf1, kf1, acc, 0, 0, 0);\
        int colg = (t) * 64 + nt * 16 + m15;                                  \
        _Pragma("unroll")                                                     \
        for (int reg = 0; reg < 4; ++reg) {                                   \
            int rowg = rowbase + q4 * 4 + reg;                                \
            float p = (colg <= rowg)                                          \
                ? exp2f(fminf(acc[reg] * 0.180336880f, 80.f)) : 0.f;          \
            lsum[reg] += p;                                                   \
            Ps[w][q4 * 4 + reg][nt * 16 + m15] = p;                           \
        }                                                                     \
    }                                                                         \
    _Pragma("unroll")                                                         \
    for (int ch = 0; ch < 2; ++ch) {                                          \
        f32x4 pa = *reinterpret_cast<const f32x4*>(                           \
            &Ps[w][m15][ch * 32 + q4 * 8]);                                   \
        f32x4 pb = *reinterpret_cast<const f32x4*>(                           \
            &Ps[w][m15][ch * 32 + q4 * 8 + 4]);                               \
        union { bf16x8 v; short s[8]; } tb;                                   \
        tb.s[0] = f2bf(pa[0]); tb.s[1] = f2bf(pa[1]);                         \
        tb.s[2] = f2bf(pa[2]); tb.s[3] = f2bf(pa[3]);                         \
        tb.s[4] = f2bf(pb[0]); tb.s[5] = f2bf(pb[1]);                         \
        tb.s[6] = f2bf(pb[2]); tb.s[7] = f2bf(pb[3]);                         \
        pf_[ch] = tb.v;                                                       \
    }                                                                         \
    _Pragma("unroll")                                                         \
    for (int nt2 = 0; nt2 < 4; ++nt2) {                                       \
        bf16x8 vf0 = *reinterpret_cast<const bf16x8*>(                        \
            &Vt[bf_][nt2 * 16 + m15][(q4 ^ xr_) * 8]);                        \
        bf16x8 vf1 = *reinterpret_cast<const bf16x8*>(                        \
            &Vt[bf_][nt2 * 16 + m15][((4 + q4) ^ xr_) * 8]);                  \
        o4[nt2] = __builtin_amdgcn_mfma_f32_16x16x32_bf16(                    \
            pf_[0], vf0, o4[nt2], 0, 0, 0);                                   \
        o4[nt2] = __builtin_amdgcn_mfma_f32_16x16x32_bf16(                    \
            pf_[1], vf1, o4[nt2], 0, 0, 0);                                   \
    }                                                                         \
} while (0)

    STAGE(0, 0);
    __syncthreads();                  // t=0 tiles visible

    for (int t = 0; t <= qtB; ++t) {
        const int bf = t & 1;
        if (t < qtB) STAGE(bf ^ 1, t + 1);      // prefetch under compute
        if (t <= qt_w) COMPUTE(bf, t);
        __syncthreads();              // reads of bf done; prefetch drained
    }

#undef STAGE
#undef COMPUTE

    float invl[4];
    #pragma unroll
    for (int reg = 0; reg < 4; ++reg) {
        float l = lsum[reg];
        l += __shfl_xor(l, 1, 64);
        l += __shfl_xor(l, 2, 64);
        l += __shfl_xor(l, 4, 64);
        l += __shfl_xor(l, 8, 64);
        invl[reg] = 1.0f / l;
    }

    #pragma unroll
    for (int nt2 = 0; nt2 < 4; ++nt2)
        #pragma unroll
        for (int reg = 0; reg < 4; ++reg)
            attn_b[(size_t)(b * S_LEN + rowbase + q4 * 4 + reg) * HIDDEN
                   + h * HD + nt2 * 16 + m15] = f2bf(o4[nt2][reg] * invl[reg]);
}

extern "C" void kernel_launch(void* const* d_in, const int* in_sizes, int n_in,
                              void* d_out, int out_size, void* d_ws, size_t ws_size,
                              hipStream_t stream) {
    // inputs: hidden_states, attention_mask, Wq, Wk, Wv, Wo — all fp32.
    // causal mask handled analytically; d_in[1] unused.
    const float* X  = (const float*)d_in[0];
    const float* Wq = (const float*)d_in[2];
    const float* Wk = (const float*)d_in[3];
    const float* Wv = (const float*)d_in[4];
    const float* Wo = (const float*)d_in[5];
    float* out = (float*)d_out;

    // workspace layout (bf16 shorts unless noted):
    short*  qkvb  = (short*)d_ws;                           // [2048][3072]  12.6 MB
    short*  Xb    = qkvb + (size_t)M_ROWS * LDQKV;          // [2048][2048]   8.4 MB
    short*  Wqkvt = Xb + (size_t)HIDDEN * HIDDEN;           // [3072][2048]  12.6 MB
    short*  Wot   = Wqkvt + (size_t)LDQKV * HIDDEN;         // [2048][2048]   8.4 MB
    short*  vt_g  = Wot + (size_t)HIDDEN * HIDDEN;          // [16*64][1024]  2.1 MB
    float2* cs2   = (float2*)(vt_g + (size_t)16 * 64 * S_LEN); // [1024][32]  256 KB
    short*  attn_b = Xb;   // alias: Xb dead after gemm1

    conv_all_kernel<<<dim3(32, 32, 5), dim3(256), 0, stream>>>(
        X, Wq, Wk, Wv, Wo, Xb, Wqkvt, Wot, cs2);

    // QKV projection with fused RoPE + fused V-transpose, bf16 out
    gemm_bf16_kernel<true><<<dim3(24, 16), dim3(256), 0, stream>>>(
        Xb, Wqkvt, nullptr, qkvb, vt_g, cs2, 2048, LDQKV);
    attn_kernel<<<dim3(8, 32, 2), dim3(512), 0, stream>>>(qkvb, vt_g, attn_b);
    gemm_bf16_kernel<false><<<dim3(16, 16), dim3(256), 0, stream>>>(
        attn_b, Wot, out, nullptr, nullptr, nullptr, 2048, HIDDEN);
}

// Round 4
// 194.462 us; speedup vs baseline: 1.1240x; 1.1240x over previous
//
#include <hip/hip_runtime.h>
#include <hip/hip_bf16.h>
#include <math.h>

#define S_LEN 1024
#define BATCH 2
#define HIDDEN 2048
#define NQH 32
#define NKVH 8
#define HD 64
#define LDQKV 3072          // Q(2048) | K(512) | V(512)
#define M_ROWS (BATCH * S_LEN)

typedef __attribute__((ext_vector_type(8))) short bf16x8;
typedef __attribute__((ext_vector_type(4))) float f32x4;

typedef unsigned int uint32_g __attribute__((address_space(1)));
typedef unsigned int uint32_l __attribute__((address_space(3)));

// async global->LDS, 16 B per lane; lds base MUST be wave-uniform,
// HW writes lane i at base + i*16 (m97/m104 semantics).
static __device__ __forceinline__ void load_lds16(const void* g, void* l) {
    __builtin_amdgcn_global_load_lds((const uint32_g*)g, (uint32_l*)l, 16, 0, 0);
}

static __device__ __forceinline__ short f2bf(float f) {
    union { __hip_bfloat16 h; short s; } cv;
    cv.h = __float2bfloat16(f);   // RNE
    return cv.s;
}

// ---------------------------------------------------------------------------
// Single pre-pass launch:
//  z=0..3 : weights fp32 [K][N] -> bf16 transposed [N][K] (64x64 LDS tiles)
//  z=4    : X fp32->bf16 flat convert + RoPE cos/sin table
// ---------------------------------------------------------------------------
__global__ __launch_bounds__(256) void conv_all_kernel(
    const float* __restrict__ X,
    const float* __restrict__ Wq, const float* __restrict__ Wk,
    const float* __restrict__ Wv, const float* __restrict__ Wo,
    short* __restrict__ Xb, short* __restrict__ Wqkvt, short* __restrict__ Wot,
    float2* __restrict__ cs2)
{
    __shared__ short Ts[64][68];
    const int tid = threadIdx.x;

    if (blockIdx.z == 4) {
        int flat = blockIdx.y * 32 + blockIdx.x;        // 0..1023
        size_t base = (size_t)flat * 4096 + (size_t)tid * 16;
        #pragma unroll
        for (int rep = 0; rep < 2; ++rep) {
            size_t i = base + rep * 8;
            float4 a = *reinterpret_cast<const float4*>(X + i);
            float4 b = *reinterpret_cast<const float4*>(X + i + 4);
            union { bf16x8 v; short s[8]; } t;
            t.s[0] = f2bf(a.x); t.s[1] = f2bf(a.y); t.s[2] = f2bf(a.z); t.s[3] = f2bf(a.w);
            t.s[4] = f2bf(b.x); t.s[5] = f2bf(b.y); t.s[6] = f2bf(b.z); t.s[7] = f2bf(b.w);
            *reinterpret_cast<bf16x8*>(Xb + i) = t.v;
        }
        if (flat < 128) {
            int g = flat * 256 + tid;                   // 32768 entries
            int s = g >> 5, i = g & 31;
            float inv_freq = 1.0f / powf(10000.0f, (float)i / 32.0f);
            float freq = (float)s * inv_freq;           // fp32 like reference
            double sn, cs;
            sincos((double)freq, &sn, &cs);
            cs2[g] = make_float2((float)cs, (float)sn);
        }
        return;
    }

    const float* src; short* dst; int N;
    switch (blockIdx.z) {
        case 0: src = Wq; dst = Wqkvt;                         N = 2048; break;
        case 1: src = Wk; dst = Wqkvt + (size_t)2048 * 2048;   N = 512;  break;
        case 2: src = Wv; dst = Wqkvt + (size_t)2560 * 2048;   N = 512;  break;
        default: src = Wo; dst = Wot;                          N = 2048; break;
    }
    const int n0 = blockIdx.x * 64, k0 = blockIdx.y * 64;
    if (n0 >= N) return;

    #pragma unroll
    for (int rep = 0; rep < 4; ++rep) {
        int idx = rep * 256 + tid;
        int row = idx >> 4, c4 = (idx & 15) * 4;
        float4 v = *reinterpret_cast<const float4*>(
            src + (size_t)(k0 + row) * N + n0 + c4);
        ushort4 u;
        u.x = (unsigned short)f2bf(v.x); u.y = (unsigned short)f2bf(v.y);
        u.z = (unsigned short)f2bf(v.z); u.w = (unsigned short)f2bf(v.w);
        *reinterpret_cast<ushort4*>(&Ts[row][c4]) = u;
    }
    __syncthreads();
    #pragma unroll
    for (int rep = 0; rep < 2; ++rep) {
        int idx = rep * 256 + tid;
        int n = idx >> 3, kc = (idx & 7) * 8;
        union { bf16x8 v; short s[8]; } t;
        #pragma unroll
        for (int j = 0; j < 8; ++j) t.s[j] = Ts[kc + j][n];
        *reinterpret_cast<bf16x8*>(dst + (size_t)(n0 + n) * 2048 + k0 + kc) = t.v;
    }
}

// ---------------------------------------------------------------------------
// bf16 MFMA GEMM v3: 128x64 tile (grid-rich: 768/512 blocks = 3/2 per CU),
// BK=64, ping-pong double-buffered LDS with prefetch-before-compute:
// per K-step issue global_load_lds for tile kt+1 into buf^1, compute buf,
// ONE barrier (drain covered by the compute phase). XOR-swizzled chunks
// (chunk ^= row&7). 4 waves, each 32 rows x 64 cols, acc[2][4].
// ROPE_BF16 epilogues: RoPE for Q/K heads; fused V-transpose to vt_g
// (identical to the R1/R2-verified mapping).
// ---------------------------------------------------------------------------
template <bool ROPE_BF16>
__global__ __launch_bounds__(256) void gemm_bf16_kernel(
    const short* __restrict__ A, const short* __restrict__ Bt,
    float* __restrict__ C, short* __restrict__ Cb,
    short* __restrict__ vt_g,
    const float2* __restrict__ cs2, int K, int ldc)
{
    const int n0 = blockIdx.x * 64, m0 = blockIdx.y * 128;
    const int tid = threadIdx.x;
    const int w = tid >> 6, lane = tid & 63;
    const int m15 = lane & 15, q4 = lane >> 4;

    __shared__ short SL[2][128 * 64 + 64 * 64];   // ping-pong As|Bs (2x24 KB)

    f32x4 acc[2][4];
    #pragma unroll
    for (int i = 0; i < 2; ++i)
        #pragma unroll
        for (int j = 0; j < 4; ++j) acc[i][j] = (f32x4){0.f, 0.f, 0.f, 0.f};

    const int srow = lane >> 3;      // row within 8-row issue
    const int pchunk = lane & 7;     // physical 16B chunk

// stage K-tile at k0_ into buffer bf_ (async, wave-uniform LDS bases)
#define GSTAGE(bf_, k0_) do {                                                 \
    short (*As_)[64] = (short(*)[64])SL[bf_];                                 \
    short (*Bs_)[64] = (short(*)[64])(SL[bf_] + 128 * 64);                    \
    _Pragma("unroll")                                                         \
    for (int r = 0; r < 4; ++r) {                                             \
        int row = (w * 4 + r) * 8 + srow;          /* 0..127 */               \
        int lchunk = pchunk ^ (row & 7);                                      \
        load_lds16(A + (size_t)(m0 + row) * K + (k0_) + lchunk * 8,           \
                   &As_[(w * 4 + r) * 8][0]);                                 \
    }                                                                         \
    _Pragma("unroll")                                                         \
    for (int r = 0; r < 2; ++r) {                                             \
        int row = (w * 2 + r) * 8 + srow;          /* 0..63 */                \
        int lchunk = pchunk ^ (row & 7);                                      \
        load_lds16(Bt + (size_t)(n0 + row) * K + (k0_) + lchunk * 8,          \
                   &Bs_[(w * 2 + r) * 8][0]);                                 \
    }                                                                         \
} while (0)

    GSTAGE(0, 0);
    __syncthreads();                 // tile 0 visible

    const int nkt = K >> 6;
    for (int kt = 0; kt < nkt; ++kt) {
        const int bf = kt & 1;
        if (kt + 1 < nkt) GSTAGE(bf ^ 1, (kt + 1) * 64);   // prefetch

        short (*As)[64] = (short(*)[64])SL[bf];
        short (*Bs)[64] = (short(*)[64])(SL[bf] + 128 * 64);
        #pragma unroll
        for (int ch = 0; ch < 2; ++ch) {
            bf16x8 af[2], bff[4];
            #pragma unroll
            for (int mt = 0; mt < 2; ++mt) {
                int row = w * 32 + mt * 16 + m15;
                af[mt] = *reinterpret_cast<const bf16x8*>(
                    &As[row][(((ch * 4 + q4) ^ (row & 7))) * 8]);
            }
            #pragma unroll
            for (int nt = 0; nt < 4; ++nt) {
                int row = nt * 16 + m15;
                bff[nt] = *reinterpret_cast<const bf16x8*>(
                    &Bs[row][(((ch * 4 + q4) ^ (row & 7))) * 8]);
            }
            #pragma unroll
            for (int mt = 0; mt < 2; ++mt)
                #pragma unroll
                for (int nt = 0; nt < 4; ++nt)
                    acc[mt][nt] = __builtin_amdgcn_mfma_f32_16x16x32_bf16(
                        af[mt], bff[nt], acc[mt][nt], 0, 0, 0);
        }
        __syncthreads();             // reads of bf done; prefetch drained
    }
#undef GSTAGE

    if (!ROPE_BF16) {
        #pragma unroll
        for (int mt = 0; mt < 2; ++mt)
            #pragma unroll
            for (int nt = 0; nt < 4; ++nt)
                #pragma unroll
                for (int reg = 0; reg < 4; ++reg)
                    C[(size_t)(m0 + w * 32 + mt * 16 + q4 * 4 + reg) * ldc
                      + n0 + nt * 16 + m15] = acc[mt][nt][reg];
    } else if (n0 < 2560) {
        // Q or K head: rotate (x1 = nt 0,1; x2 = nt 2,3)
        #pragma unroll
        for (int mt = 0; mt < 2; ++mt) {
            #pragma unroll
            for (int reg = 0; reg < 4; ++reg) {
                int row = m0 + w * 32 + mt * 16 + q4 * 4 + reg;
                int s = row & (S_LEN - 1);
                float2 t0 = cs2[s * 32 + m15];
                float2 t1 = cs2[s * 32 + 16 + m15];
                float a0 = acc[mt][0][reg], a1 = acc[mt][1][reg];
                float a2 = acc[mt][2][reg], a3 = acc[mt][3][reg];
                size_t base = (size_t)row * ldc + n0 + m15;
                Cb[base +  0] = f2bf(a0 * t0.x - a2 * t0.y);
                Cb[base + 16] = f2bf(a1 * t1.x - a3 * t1.y);
                Cb[base + 32] = f2bf(a2 * t0.x + a0 * t0.y);
                Cb[base + 48] = f2bf(a3 * t1.x + a1 * t1.y);
            }
        }
    } else {
        // V head: transpose via LDS, write vt_g[(b*8+kvh)*64+dim][1024]
        __syncthreads();             // all waves past the K-loop
        short (*VT)[136] = (short(*)[136])SL[0];   // [64 dim][128 key +8 pad]
        #pragma unroll
        for (int mt = 0; mt < 2; ++mt) {
            #pragma unroll
            for (int nt = 0; nt < 4; ++nt) {
                ushort4 u;
                u.x = (unsigned short)f2bf(acc[mt][nt][0]);
                u.y = (unsigned short)f2bf(acc[mt][nt][1]);
                u.z = (unsigned short)f2bf(acc[mt][nt][2]);
                u.w = (unsigned short)f2bf(acc[mt][nt][3]);
                *reinterpret_cast<ushort4*>(
                    &VT[nt * 16 + m15][w * 32 + mt * 16 + q4 * 4]) = u;
            }
        }
        __syncthreads();
        const int kvh = (n0 - 2560) >> 6;
        const int b = m0 >> 10, k0loc = m0 & (S_LEN - 1);
        const int dim = tid >> 2, kc = (tid & 3) * 32;
        short* dst = vt_g + (size_t)((b * 8 + kvh) * 64 + dim) * S_LEN + k0loc + kc;
        #pragma unroll
        for (int u = 0; u < 4; ++u)
            *reinterpret_cast<bf16x8*>(dst + u * 8) =
                *reinterpret_cast<const bf16x8*>(&VT[dim][kc + u * 8]);
    }
}

// ---------------------------------------------------------------------------
// Causal GQA attention v5: paired q-tiles, 8 waves (512 thr) per block.
// Block (i, h, b): waves 0-3 own heavy q-tile qtB=15-i (16 q-rows each),
// waves 4-7 own light q-tile qtA=i (idle for t > qtA, still stage+barrier).
// Grid 8x32x2 = 512 blocks x 8 waves = 16 waves/CU = 4 waves/SIMD.
// K/V ping-pong staged via global_load_lds w16, prefetch-before-compute,
// one barrier per tile. fp32 no-max softmax p = exp2(acc * 0.125*log2e),
// clamp 80, analytic causal mask. (unchanged — known-good)
// ---------------------------------------------------------------------------
__global__ __launch_bounds__(512) void attn_kernel(
    const short* __restrict__ qkvb, const short* __restrict__ vt_g,
    short* __restrict__ attn_b)
{
    const int i  = blockIdx.x;        // 0..7
    const int h  = blockIdx.y;
    const int b  = blockIdx.z;
    const int qtA = i;                // 0..7   (light q-tile)
    const int qtB = 15 - i;           // 15..8  (heavy q-tile)
    const int tid = threadIdx.x;
    const int w = tid >> 6, lane = tid & 63;
    const int kvh = h >> 2;
    const int m15 = lane & 15, q4 = lane >> 4;

    __shared__ short Ks[2][64][64];   // [buf][key][dim], XOR-swizzled chunks
    __shared__ short Vt[2][64][64];   // [buf][dim][key], XOR-swizzled chunks
    __shared__ float Ps[8][16][68];   // per-wave P [row][key] fp32

    // wave -> q-tile assignment
    const int qt_w = (w < 4) ? qtB : qtA;
    const int rowbase = qt_w * 64 + (w & 3) * 16;

    const bf16x8 qf0 = *reinterpret_cast<const bf16x8*>(
        qkvb + (size_t)(b * S_LEN + rowbase + m15) * LDQKV + h * HD + q4 * 8);
    const bf16x8 qf1 = *reinterpret_cast<const bf16x8*>(
        qkvb + (size_t)(b * S_LEN + rowbase + m15) * LDQKV + h * HD + 32 + q4 * 8);

    f32x4 o4[4];
    #pragma unroll
    for (int k = 0; k < 4; ++k) o4[k] = (f32x4){0.f, 0.f, 0.f, 0.f};
    float lsum[4] = {0.f, 0.f, 0.f, 0.f};

    const int r8 = lane >> 3, p8 = lane & 7;
    const int lch = (p8 ^ r8) * 8;    // logical chunk offset to fetch (shorts)
    const short* kbase = qkvb + (size_t)(b * S_LEN) * LDQKV + 2048 + kvh * HD;
    const short* vbase = vt_g + (size_t)(b * 8 + kvh) * 64 * S_LEN;

// wave w stages Ks rows w*8..+7 (keys) and Vt rows w*8..+7 (dims) of buf
#define STAGE(bf_, t) do {                                                    \
    int row_ = w * 8 + r8;                                                    \
    load_lds16(kbase + (size_t)((t) * 64 + row_) * LDQKV + lch,               \
               &Ks[bf_][w * 8][0]);                                           \
    load_lds16(vbase + (size_t)row_ * S_LEN + (t) * 64 + lch,                 \
               &Vt[bf_][w * 8][0]);                                           \
} while (0)

// QK^T + mask + exp into per-wave Ps; P->bf16; PV. Identical math to v3/v4.
#define COMPUTE(bf_, t) do {                                                  \
    const int xr_ = m15 & 7;                                                  \
    bf16x8 pf_[2];                                                            \
    _Pragma("unroll")                                                         \
    for (int nt = 0; nt < 4; ++nt) {                                          \
        f32x4 acc = (f32x4){0.f, 0.f, 0.f, 0.f};                              \
        bf16x8 kf0 = *reinterpret_cast<const bf16x8*>(                        \
            &Ks[bf_][nt * 16 + m15][(q4 ^ xr_) * 8]);                         \
        bf16x8 kf1 = *reinterpret_cast<const bf16x8*>(                        \
            &Ks[bf_][nt * 16 + m15][((4 + q4) ^ xr_) * 8]);                   \
        acc = __builtin_amdgcn_mfma_f32_16x16x32_bf16(qf0, kf0, acc, 0, 0, 0);\
        acc = __builtin_amdgcn_mfma_f32_16x16x32_bf16(qf1, kf1, acc, 0, 0, 0);\
        int colg = (t) * 64 + nt * 16 + m15;                                  \
        _Pragma("unroll")                                                     \
        for (int reg = 0; reg < 4; ++reg) {                                   \
            int rowg = rowbase + q4 * 4 + reg;                                \
            float p = (colg <= rowg)                                          \
                ? exp2f(fminf(acc[reg] * 0.180336880f, 80.f)) : 0.f;          \
            lsum[reg] += p;                                                   \
            Ps[w][q4 * 4 + reg][nt * 16 + m15] = p;                           \
        }                                                                     \
    }                                                                         \
    _Pragma("unroll")                                                         \
    for (int ch = 0; ch < 2; ++ch) {                                          \
        f32x4 pa = *reinterpret_cast<const f32x4*>(                           \
            &Ps[w][m15][ch * 32 + q4 * 8]);                                   \
        f32x4 pb = *reinterpret_cast<const f32x4*>(                           \
            &Ps[w][m15][ch * 32 + q4 * 8 + 4]);                               \
        union { bf16x8 v; short s[8]; } tb;                                   \
        tb.s[0] = f2bf(pa[0]); tb.s[1] = f2bf(pa[1]);                         \
        tb.s[2] = f2bf(pa[2]); tb.s[3] = f2bf(pa[3]);                         \
        tb.s[4] = f2bf(pb[0]); tb.s[5] = f2bf(pb[1]);                         \
        tb.s[6] = f2bf(pb[2]); tb.s[7] = f2bf(pb[3]);                         \
        pf_[ch] = tb.v;                                                       \
    }                                                                         \
    _Pragma("unroll")                                                         \
    for (int nt2 = 0; nt2 < 4; ++nt2) {                                       \
        bf16x8 vf0 = *reinterpret_cast<const bf16x8*>(                        \
            &Vt[bf_][nt2 * 16 + m15][(q4 ^ xr_) * 8]);                        \
        bf16x8 vf1 = *reinterpret_cast<const bf16x8*>(                        \
            &Vt[bf_][nt2 * 16 + m15][((4 + q4) ^ xr_) * 8]);                  \
        o4[nt2] = __builtin_amdgcn_mfma_f32_16x16x32_bf16(                    \
            pf_[0], vf0, o4[nt2], 0, 0, 0);                                   \
        o4[nt2] = __builtin_amdgcn_mfma_f32_16x16x32_bf16(                    \
            pf_[1], vf1, o4[nt2], 0, 0, 0);                                   \
    }                                                                         \
} while (0)

    STAGE(0, 0);
    __syncthreads();                  // t=0 tiles visible

    for (int t = 0; t <= qtB; ++t) {
        const int bf = t & 1;
        if (t < qtB) STAGE(bf ^ 1, t + 1);      // prefetch under compute
        if (t <= qt_w) COMPUTE(bf, t);
        __syncthreads();              // reads of bf done; prefetch drained
    }

#undef STAGE
#undef COMPUTE

    float invl[4];
    #pragma unroll
    for (int reg = 0; reg < 4; ++reg) {
        float l = lsum[reg];
        l += __shfl_xor(l, 1, 64);
        l += __shfl_xor(l, 2, 64);
        l += __shfl_xor(l, 4, 64);
        l += __shfl_xor(l, 8, 64);
        invl[reg] = 1.0f / l;
    }

    #pragma unroll
    for (int nt2 = 0; nt2 < 4; ++nt2)
        #pragma unroll
        for (int reg = 0; reg < 4; ++reg)
            attn_b[(size_t)(b * S_LEN + rowbase + q4 * 4 + reg) * HIDDEN
                   + h * HD + nt2 * 16 + m15] = f2bf(o4[nt2][reg] * invl[reg]);
}

extern "C" void kernel_launch(void* const* d_in, const int* in_sizes, int n_in,
                              void* d_out, int out_size, void* d_ws, size_t ws_size,
                              hipStream_t stream) {
    // inputs: hidden_states, attention_mask, Wq, Wk, Wv, Wo — all fp32.
    // causal mask handled analytically; d_in[1] unused.
    const float* X  = (const float*)d_in[0];
    const float* Wq = (const float*)d_in[2];
    const float* Wk = (const float*)d_in[3];
    const float* Wv = (const float*)d_in[4];
    const float* Wo = (const float*)d_in[5];
    float* out = (float*)d_out;

    // workspace layout (bf16 shorts unless noted):
    short*  qkvb  = (short*)d_ws;                           // [2048][3072]  12.6 MB
    short*  Xb    = qkvb + (size_t)M_ROWS * LDQKV;          // [2048][2048]   8.4 MB
    short*  Wqkvt = Xb + (size_t)HIDDEN * HIDDEN;           // [3072][2048]  12.6 MB
    short*  Wot   = Wqkvt + (size_t)LDQKV * HIDDEN;         // [2048][2048]   8.4 MB
    short*  vt_g  = Wot + (size_t)HIDDEN * HIDDEN;          // [16*64][1024]  2.1 MB
    float2* cs2   = (float2*)(vt_g + (size_t)16 * 64 * S_LEN); // [1024][32]  256 KB
    short*  attn_b = Xb;   // alias: Xb dead after gemm1

    conv_all_kernel<<<dim3(32, 32, 5), dim3(256), 0, stream>>>(
        X, Wq, Wk, Wv, Wo, Xb, Wqkvt, Wot, cs2);

    // QKV projection with fused RoPE + fused V-transpose, bf16 out
    gemm_bf16_kernel<true><<<dim3(48, 16), dim3(256), 0, stream>>>(
        Xb, Wqkvt, nullptr, qkvb, vt_g, cs2, 2048, LDQKV);
    attn_kernel<<<dim3(8, 32, 2), dim3(512), 0, stream>>>(qkvb, vt_g, attn_b);
    gemm_bf16_kernel<false><<<dim3(32, 16), dim3(256), 0, stream>>>(
        attn_b, Wot, out, nullptr, nullptr, nullptr, 2048, HIDDEN);
}

// Round 5
// 191.651 us; speedup vs baseline: 1.1405x; 1.0147x over previous
//
#include <hip/hip_runtime.h>
#include <hip/hip_bf16.h>
#include <math.h>

#define S_LEN 1024
#define BATCH 2
#define HIDDEN 2048
#define NQH 32
#define NKVH 8
#define HD 64
#define LDQKV 3072          // Q(2048) | K(512) | V(512)
#define M_ROWS (BATCH * S_LEN)

typedef __attribute__((ext_vector_type(8))) short bf16x8;
typedef __attribute__((ext_vector_type(4))) float f32x4;

typedef unsigned int uint32_g __attribute__((address_space(1)));
typedef unsigned int uint32_l __attribute__((address_space(3)));

// async global->LDS, 16 B per lane; lds base MUST be wave-uniform,
// HW writes lane i at base + i*16 (m97/m104 semantics).
static __device__ __forceinline__ void load_lds16(const void* g, void* l) {
    __builtin_amdgcn_global_load_lds((const uint32_g*)g, (uint32_l*)l, 16, 0, 0);
}

static __device__ __forceinline__ short f2bf(float f) {
    union { __hip_bfloat16 h; short s; } cv;
    cv.h = __float2bfloat16(f);   // RNE
    return cv.s;
}

// ---------------------------------------------------------------------------
// Single pre-pass launch:
//  z=0..3 : weights fp32 [K][N] -> bf16 transposed [N][K] (64x64 LDS tiles)
//  z=4    : X fp32->bf16 flat convert + RoPE cos/sin table
// ---------------------------------------------------------------------------
__global__ __launch_bounds__(256) void conv_all_kernel(
    const float* __restrict__ X,
    const float* __restrict__ Wq, const float* __restrict__ Wk,
    const float* __restrict__ Wv, const float* __restrict__ Wo,
    short* __restrict__ Xb, short* __restrict__ Wqkvt, short* __restrict__ Wot,
    float2* __restrict__ cs2)
{
    __shared__ short Ts[64][68];
    const int tid = threadIdx.x;

    if (blockIdx.z == 4) {
        int flat = blockIdx.y * 32 + blockIdx.x;        // 0..1023
        size_t base = (size_t)flat * 4096 + (size_t)tid * 16;
        #pragma unroll
        for (int rep = 0; rep < 2; ++rep) {
            size_t i = base + rep * 8;
            float4 a = *reinterpret_cast<const float4*>(X + i);
            float4 b = *reinterpret_cast<const float4*>(X + i + 4);
            union { bf16x8 v; short s[8]; } t;
            t.s[0] = f2bf(a.x); t.s[1] = f2bf(a.y); t.s[2] = f2bf(a.z); t.s[3] = f2bf(a.w);
            t.s[4] = f2bf(b.x); t.s[5] = f2bf(b.y); t.s[6] = f2bf(b.z); t.s[7] = f2bf(b.w);
            *reinterpret_cast<bf16x8*>(Xb + i) = t.v;
        }
        if (flat < 128) {
            int g = flat * 256 + tid;                   // 32768 entries
            int s = g >> 5, i = g & 31;
            float inv_freq = 1.0f / powf(10000.0f, (float)i / 32.0f);
            float freq = (float)s * inv_freq;           // fp32 like reference
            double sn, cs;
            sincos((double)freq, &sn, &cs);
            cs2[g] = make_float2((float)cs, (float)sn);
        }
        return;
    }

    const float* src; short* dst; int N;
    switch (blockIdx.z) {
        case 0: src = Wq; dst = Wqkvt;                         N = 2048; break;
        case 1: src = Wk; dst = Wqkvt + (size_t)2048 * 2048;   N = 512;  break;
        case 2: src = Wv; dst = Wqkvt + (size_t)2560 * 2048;   N = 512;  break;
        default: src = Wo; dst = Wot;                          N = 2048; break;
    }
    const int n0 = blockIdx.x * 64, k0 = blockIdx.y * 64;
    if (n0 >= N) return;

    #pragma unroll
    for (int rep = 0; rep < 4; ++rep) {
        int idx = rep * 256 + tid;
        int row = idx >> 4, c4 = (idx & 15) * 4;
        float4 v = *reinterpret_cast<const float4*>(
            src + (size_t)(k0 + row) * N + n0 + c4);
        ushort4 u;
        u.x = (unsigned short)f2bf(v.x); u.y = (unsigned short)f2bf(v.y);
        u.z = (unsigned short)f2bf(v.z); u.w = (unsigned short)f2bf(v.w);
        *reinterpret_cast<ushort4*>(&Ts[row][c4]) = u;
    }
    __syncthreads();
    #pragma unroll
    for (int rep = 0; rep < 2; ++rep) {
        int idx = rep * 256 + tid;
        int n = idx >> 3, kc = (idx & 7) * 8;
        union { bf16x8 v; short s[8]; } t;
        #pragma unroll
        for (int j = 0; j < 8; ++j) t.s[j] = Ts[kc + j][n];
        *reinterpret_cast<bf16x8*>(dst + (size_t)(n0 + n) * 2048 + k0 + kc) = t.v;
    }
}

// ---------------------------------------------------------------------------
// bf16 MFMA GEMM v3: 128x64 tile (grid-rich: 768/512 blocks = 3/2 per CU),
// BK=64, ping-pong double-buffered LDS with prefetch-before-compute:
// per K-step issue global_load_lds for tile kt+1 into buf^1, compute buf,
// ONE barrier (drain covered by the compute phase). XOR-swizzled chunks
// (chunk ^= row&7). 4 waves, each 32 rows x 64 cols, acc[2][4].
// ROPE_BF16 epilogues: RoPE for Q/K heads; fused V-transpose to vt_g.
// (unchanged from R4 — known-good)
// ---------------------------------------------------------------------------
template <bool ROPE_BF16>
__global__ __launch_bounds__(256) void gemm_bf16_kernel(
    const short* __restrict__ A, const short* __restrict__ Bt,
    float* __restrict__ C, short* __restrict__ Cb,
    short* __restrict__ vt_g,
    const float2* __restrict__ cs2, int K, int ldc)
{
    const int n0 = blockIdx.x * 64, m0 = blockIdx.y * 128;
    const int tid = threadIdx.x;
    const int w = tid >> 6, lane = tid & 63;
    const int m15 = lane & 15, q4 = lane >> 4;

    __shared__ short SL[2][128 * 64 + 64 * 64];   // ping-pong As|Bs (2x24 KB)

    f32x4 acc[2][4];
    #pragma unroll
    for (int i = 0; i < 2; ++i)
        #pragma unroll
        for (int j = 0; j < 4; ++j) acc[i][j] = (f32x4){0.f, 0.f, 0.f, 0.f};

    const int srow = lane >> 3;      // row within 8-row issue
    const int pchunk = lane & 7;     // physical 16B chunk

// stage K-tile at k0_ into buffer bf_ (async, wave-uniform LDS bases)
#define GSTAGE(bf_, k0_) do {                                                 \
    short (*As_)[64] = (short(*)[64])SL[bf_];                                 \
    short (*Bs_)[64] = (short(*)[64])(SL[bf_] + 128 * 64);                    \
    _Pragma("unroll")                                                         \
    for (int r = 0; r < 4; ++r) {                                             \
        int row = (w * 4 + r) * 8 + srow;          /* 0..127 */               \
        int lchunk = pchunk ^ (row & 7);                                      \
        load_lds16(A + (size_t)(m0 + row) * K + (k0_) + lchunk * 8,           \
                   &As_[(w * 4 + r) * 8][0]);                                 \
    }                                                                         \
    _Pragma("unroll")                                                         \
    for (int r = 0; r < 2; ++r) {                                             \
        int row = (w * 2 + r) * 8 + srow;          /* 0..63 */                \
        int lchunk = pchunk ^ (row & 7);                                      \
        load_lds16(Bt + (size_t)(n0 + row) * K + (k0_) + lchunk * 8,          \
                   &Bs_[(w * 2 + r) * 8][0]);                                 \
    }                                                                         \
} while (0)

    GSTAGE(0, 0);
    __syncthreads();                 // tile 0 visible

    const int nkt = K >> 6;
    for (int kt = 0; kt < nkt; ++kt) {
        const int bf = kt & 1;
        if (kt + 1 < nkt) GSTAGE(bf ^ 1, (kt + 1) * 64);   // prefetch

        short (*As)[64] = (short(*)[64])SL[bf];
        short (*Bs)[64] = (short(*)[64])(SL[bf] + 128 * 64);
        #pragma unroll
        for (int ch = 0; ch < 2; ++ch) {
            bf16x8 af[2], bff[4];
            #pragma unroll
            for (int mt = 0; mt < 2; ++mt) {
                int row = w * 32 + mt * 16 + m15;
                af[mt] = *reinterpret_cast<const bf16x8*>(
                    &As[row][(((ch * 4 + q4) ^ (row & 7))) * 8]);
            }
            #pragma unroll
            for (int nt = 0; nt < 4; ++nt) {
                int row = nt * 16 + m15;
                bff[nt] = *reinterpret_cast<const bf16x8*>(
                    &Bs[row][(((ch * 4 + q4) ^ (row & 7))) * 8]);
            }
            #pragma unroll
            for (int mt = 0; mt < 2; ++mt)
                #pragma unroll
                for (int nt = 0; nt < 4; ++nt)
                    acc[mt][nt] = __builtin_amdgcn_mfma_f32_16x16x32_bf16(
                        af[mt], bff[nt], acc[mt][nt], 0, 0, 0);
        }
        __syncthreads();             // reads of bf done; prefetch drained
    }
#undef GSTAGE

    if (!ROPE_BF16) {
        #pragma unroll
        for (int mt = 0; mt < 2; ++mt)
            #pragma unroll
            for (int nt = 0; nt < 4; ++nt)
                #pragma unroll
                for (int reg = 0; reg < 4; ++reg)
                    C[(size_t)(m0 + w * 32 + mt * 16 + q4 * 4 + reg) * ldc
                      + n0 + nt * 16 + m15] = acc[mt][nt][reg];
    } else if (n0 < 2560) {
        // Q or K head: rotate (x1 = nt 0,1; x2 = nt 2,3)
        #pragma unroll
        for (int mt = 0; mt < 2; ++mt) {
            #pragma unroll
            for (int reg = 0; reg < 4; ++reg) {
                int row = m0 + w * 32 + mt * 16 + q4 * 4 + reg;
                int s = row & (S_LEN - 1);
                float2 t0 = cs2[s * 32 + m15];
                float2 t1 = cs2[s * 32 + 16 + m15];
                float a0 = acc[mt][0][reg], a1 = acc[mt][1][reg];
                float a2 = acc[mt][2][reg], a3 = acc[mt][3][reg];
                size_t base = (size_t)row * ldc + n0 + m15;
                Cb[base +  0] = f2bf(a0 * t0.x - a2 * t0.y);
                Cb[base + 16] = f2bf(a1 * t1.x - a3 * t1.y);
                Cb[base + 32] = f2bf(a2 * t0.x + a0 * t0.y);
                Cb[base + 48] = f2bf(a3 * t1.x + a1 * t1.y);
            }
        }
    } else {
        // V head: transpose via LDS, write vt_g[(b*8+kvh)*64+dim][1024]
        __syncthreads();             // all waves past the K-loop
        short (*VT)[136] = (short(*)[136])SL[0];   // [64 dim][128 key +8 pad]
        #pragma unroll
        for (int mt = 0; mt < 2; ++mt) {
            #pragma unroll
            for (int nt = 0; nt < 4; ++nt) {
                ushort4 u;
                u.x = (unsigned short)f2bf(acc[mt][nt][0]);
                u.y = (unsigned short)f2bf(acc[mt][nt][1]);
                u.z = (unsigned short)f2bf(acc[mt][nt][2]);
                u.w = (unsigned short)f2bf(acc[mt][nt][3]);
                *reinterpret_cast<ushort4*>(
                    &VT[nt * 16 + m15][w * 32 + mt * 16 + q4 * 4]) = u;
            }
        }
        __syncthreads();
        const int kvh = (n0 - 2560) >> 6;
        const int b = m0 >> 10, k0loc = m0 & (S_LEN - 1);
        const int dim = tid >> 2, kc = (tid & 3) * 32;
        short* dst = vt_g + (size_t)((b * 8 + kvh) * 64 + dim) * S_LEN + k0loc + kc;
        #pragma unroll
        for (int u = 0; u < 4; ++u)
            *reinterpret_cast<bf16x8*>(dst + u * 8) =
                *reinterpret_cast<const bf16x8*>(&VT[dim][kc + u * 8]);
    }
}

// ---------------------------------------------------------------------------
// Causal GQA attention v6: swapped QK^T -> fully in-register softmax.
// mfma(kf, qf) computes S^T (A/B frags have identical lane layouts, so the
// same loaded registers swap roles): lane (q4,m15) holds S[key=nt*16+q4*4+reg]
// [q=m15] — 16 keys of ONE q-row. Softmax (mask hoisted to diagonal tiles,
// exp2, per-lane lsum) is register-only; P->bf16 via 8 packed u32 +
// 16 __shfl + 8 selects rebuilds the PV A-frag P[q=m15][keys q4*8..+7].
// No Ps LDS round-trip (the old 16 ds_write + 4 ds_read_b128 + 2x ~120cy
// serial latencies per tile). PV + output layout identical to v5.
// Paired q-tiles, 8 waves; K/V ping-pong via global_load_lds w16, one
// barrier per tile. LDS 32 KB.
// ---------------------------------------------------------------------------
__global__ __launch_bounds__(512, 4) void attn_kernel(
    const short* __restrict__ qkvb, const short* __restrict__ vt_g,
    short* __restrict__ attn_b)
{
    const int i  = blockIdx.x;        // 0..7
    const int h  = blockIdx.y;
    const int b  = blockIdx.z;
    const int qtA = i;                // 0..7   (light q-tile)
    const int qtB = 15 - i;           // 15..8  (heavy q-tile)
    const int tid = threadIdx.x;
    const int w = tid >> 6, lane = tid & 63;
    const int kvh = h >> 2;
    const int m15 = lane & 15, q4 = lane >> 4;

    __shared__ short Ks[2][64][64];   // [buf][key][dim], XOR-swizzled chunks
    __shared__ short Vt[2][64][64];   // [buf][dim][key], XOR-swizzled chunks

    // wave -> q-tile assignment
    const int qt_w = (w < 4) ? qtB : qtA;
    const int rowbase = qt_w * 64 + (w & 3) * 16;

    const bf16x8 qf0 = *reinterpret_cast<const bf16x8*>(
        qkvb + (size_t)(b * S_LEN + rowbase + m15) * LDQKV + h * HD + q4 * 8);
    const bf16x8 qf1 = *reinterpret_cast<const bf16x8*>(
        qkvb + (size_t)(b * S_LEN + rowbase + m15) * LDQKV + h * HD + 32 + q4 * 8);

    f32x4 o4[4];
    #pragma unroll
    for (int k = 0; k < 4; ++k) o4[k] = (f32x4){0.f, 0.f, 0.f, 0.f};
    float lsum = 0.f;                 // per-lane: q-row m15, this lane's keys

    const int r8 = lane >> 3, p8 = lane & 7;
    const int lch = (p8 ^ r8) * 8;    // logical chunk offset to fetch (shorts)
    const short* kbase = qkvb + (size_t)(b * S_LEN) * LDQKV + 2048 + kvh * HD;
    const short* vbase = vt_g + (size_t)(b * 8 + kvh) * 64 * S_LEN;

// wave w stages Ks rows w*8..+7 (keys) and Vt rows w*8..+7 (dims) of buf
#define STAGE(bf_, t) do {                                                    \
    int row_ = w * 8 + r8;                                                    \
    load_lds16(kbase + (size_t)((t) * 64 + row_) * LDQKV + lch,               \
               &Ks[bf_][w * 8][0]);                                           \
    load_lds16(vbase + (size_t)row_ * S_LEN + (t) * 64 + lch,                 \
               &Vt[bf_][w * 8][0]);                                           \
} while (0)

// swapped QK^T + in-register softmax + shfl P-exchange + PV.
#define COMPUTE(bf_, t) do {                                                  \
    const int xr_ = m15 & 7;                                                  \
    float p_[4][4];                                                           \
    _Pragma("unroll")                                                         \
    for (int nt = 0; nt < 4; ++nt) {                                          \
        f32x4 acc = (f32x4){0.f, 0.f, 0.f, 0.f};                              \
        bf16x8 kf0 = *reinterpret_cast<const bf16x8*>(                        \
            &Ks[bf_][nt * 16 + m15][(q4 ^ xr_) * 8]);                         \
        bf16x8 kf1 = *reinterpret_cast<const bf16x8*>(                        \
            &Ks[bf_][nt * 16 + m15][((4 + q4) ^ xr_) * 8]);                   \
        acc = __builtin_amdgcn_mfma_f32_16x16x32_bf16(kf0, qf0, acc, 0, 0, 0);\
        acc = __builtin_amdgcn_mfma_f32_16x16x32_bf16(kf1, qf1, acc, 0, 0, 0);\
        _Pragma("unroll")                                                     \
        for (int reg = 0; reg < 4; ++reg)                                     \
            p_[nt][reg] = exp2f(fminf(acc[reg] * 0.180336880f, 80.f));        \
    }                                                                         \
    if ((t) * 64 + 63 > rowbase) {    /* diagonal tile: causal mask */        \
        const int rowg_ = rowbase + m15;                                      \
        _Pragma("unroll")                                                     \
        for (int nt = 0; nt < 4; ++nt)                                        \
            _Pragma("unroll")                                                 \
            for (int reg = 0; reg < 4; ++reg)                                 \
                if ((t) * 64 + nt * 16 + q4 * 4 + reg > rowg_)                \
                    p_[nt][reg] = 0.f;                                        \
    }                                                                         \
    _Pragma("unroll")                                                         \
    for (int nt = 0; nt < 4; ++nt)                                            \
        _Pragma("unroll")                                                     \
        for (int reg = 0; reg < 4; ++reg) lsum += p_[nt][reg];                \
    unsigned lo_[4], hi_[4];                                                  \
    _Pragma("unroll")                                                         \
    for (int nt = 0; nt < 4; ++nt) {                                          \
        lo_[nt] = (unsigned)(unsigned short)f2bf(p_[nt][0])                   \
                | ((unsigned)(unsigned short)f2bf(p_[nt][1]) << 16);          \
        hi_[nt] = (unsigned)(unsigned short)f2bf(p_[nt][2])                   \
                | ((unsigned)(unsigned short)f2bf(p_[nt][3]) << 16);          \
    }                                                                         \
    const int La_ = ((q4 & 1) * 2) * 16 + m15;                                \
    const int Lb_ = La_ + 16;                                                 \
    const int hiH_ = q4 >> 1;                                                 \
    bf16x8 pf_[2];                                                            \
    _Pragma("unroll")                                                         \
    for (int ch = 0; ch < 2; ++ch) {                                          \
        int a0 = __shfl((int)lo_[ch * 2],     La_, 64);                       \
        int a1 = __shfl((int)hi_[ch * 2],     La_, 64);                       \
        int a2 = __shfl((int)lo_[ch * 2],     Lb_, 64);                       \
        int a3 = __shfl((int)hi_[ch * 2],     Lb_, 64);                       \
        int b0 = __shfl((int)lo_[ch * 2 + 1], La_, 64);                       \
        int b1 = __shfl((int)hi_[ch * 2 + 1], La_, 64);                       \
        int b2 = __shfl((int)lo_[ch * 2 + 1], Lb_, 64);                       \
        int b3 = __shfl((int)hi_[ch * 2 + 1], Lb_, 64);                       \
        union { int ii[4]; bf16x8 v; } u_;                                    \
        u_.ii[0] = hiH_ ? b0 : a0;                                            \
        u_.ii[1] = hiH_ ? b1 : a1;                                            \
        u_.ii[2] = hiH_ ? b2 : a2;                                            \
        u_.ii[3] = hiH_ ? b3 : a3;                                            \
        pf_[ch] = u_.v;                                                       \
    }                                                                         \
    _Pragma("unroll")                                                         \
    for (int nt2 = 0; nt2 < 4; ++nt2) {                                       \
        bf16x8 vf0 = *reinterpret_cast<const bf16x8*>(                        \
            &Vt[bf_][nt2 * 16 + m15][(q4 ^ xr_) * 8]);                        \
        bf16x8 vf1 = *reinterpret_cast<const bf16x8*>(                        \
            &Vt[bf_][nt2 * 16 + m15][((4 + q4) ^ xr_) * 8]);                  \
        o4[nt2] = __builtin_amdgcn_mfma_f32_16x16x32_bf16(                    \
            pf_[0], vf0, o4[nt2], 0, 0, 0);                                   \
        o4[nt2] = __builtin_amdgcn_mfma_f32_16x16x32_bf16(                    \
            pf_[1], vf1, o4[nt2], 0, 0, 0);                                   \
    }                                                                         \
} while (0)

    STAGE(0, 0);
    __syncthreads();                  // t=0 tiles visible

    for (int t = 0; t <= qtB; ++t) {
        const int bf = t & 1;
        if (t < qtB) STAGE(bf ^ 1, t + 1);      // prefetch under compute
        if (t <= qt_w) COMPUTE(bf, t);
        __syncthreads();              // reads of bf done; prefetch drained
    }

#undef STAGE
#undef COMPUTE

    // row-sum: lanes differing in q4 (bits 4,5) hold the same q-row m15
    float l = lsum;
    l += __shfl_xor(l, 16, 64);
    l += __shfl_xor(l, 32, 64);
    float invl = 1.0f / l;
    // redistribute to epilogue layout: lane needs 1/l of q-row q4*4+reg
    float invl4[4];
    #pragma unroll
    for (int reg = 0; reg < 4; ++reg)
        invl4[reg] = __shfl(invl, q4 * 4 + reg, 64);

    #pragma unroll
    for (int nt2 = 0; nt2 < 4; ++nt2)
        #pragma unroll
        for (int reg = 0; reg < 4; ++reg)
            attn_b[(size_t)(b * S_LEN + rowbase + q4 * 4 + reg) * HIDDEN
                   + h * HD + nt2 * 16 + m15] = f2bf(o4[nt2][reg] * invl4[reg]);
}

extern "C" void kernel_launch(void* const* d_in, const int* in_sizes, int n_in,
                              void* d_out, int out_size, void* d_ws, size_t ws_size,
                              hipStream_t stream) {
    // inputs: hidden_states, attention_mask, Wq, Wk, Wv, Wo — all fp32.
    // causal mask handled analytically; d_in[1] unused.
    const float* X  = (const float*)d_in[0];
    const float* Wq = (const float*)d_in[2];
    const float* Wk = (const float*)d_in[3];
    const float* Wv = (const float*)d_in[4];
    const float* Wo = (const float*)d_in[5];
    float* out = (float*)d_out;

    // workspace layout (bf16 shorts unless noted):
    short*  qkvb  = (short*)d_ws;                           // [2048][3072]  12.6 MB
    short*  Xb    = qkvb + (size_t)M_ROWS * LDQKV;          // [2048][2048]   8.4 MB
    short*  Wqkvt = Xb + (size_t)HIDDEN * HIDDEN;           // [3072][2048]  12.6 MB
    short*  Wot   = Wqkvt + (size_t)LDQKV * HIDDEN;         // [2048][2048]   8.4 MB
    short*  vt_g  = Wot + (size_t)HIDDEN * HIDDEN;          // [16*64][1024]  2.1 MB
    float2* cs2   = (float2*)(vt_g + (size_t)16 * 64 * S_LEN); // [1024][32]  256 KB
    short*  attn_b = Xb;   // alias: Xb dead after gemm1

    conv_all_kernel<<<dim3(32, 32, 5), dim3(256), 0, stream>>>(
        X, Wq, Wk, Wv, Wo, Xb, Wqkvt, Wot, cs2);

    // QKV projection with fused RoPE + fused V-transpose, bf16 out
    gemm_bf16_kernel<true><<<dim3(48, 16), dim3(256), 0, stream>>>(
        Xb, Wqkvt, nullptr, qkvb, vt_g, cs2, 2048, LDQKV);
    attn_kernel<<<dim3(8, 32, 2), dim3(512), 0, stream>>>(qkvb, vt_g, attn_b);
    gemm_bf16_kernel<false><<<dim3(32, 16), dim3(256), 0, stream>>>(
        attn_b, Wot, out, nullptr, nullptr, nullptr, 2048, HIDDEN);
}